// Round 1
// baseline (17.294 us; speedup 1.0000x reference)
//
#include <hip/hip_runtime.h>

#define KG 16          // gaussians per row
#define PROW (7 * KG)  // 112 floats per (b, ch) row

__global__ __launch_bounds__(256) void moe_render_kernel(
    const float* __restrict__ params,
    const int* __restrict__ hptr,
    const int* __restrict__ wptr,
    float* __restrict__ out,
    int N)
{
    const int a = blockIdx.y;                 // row index in [0, A)
    const int H = *hptr;
    const int W = *wptr;
    const int n = blockIdx.x * blockDim.x + threadIdx.x;

    __shared__ float smux[KG], smuy[KG], ss0[KG], ss1[KG], swt[KG];

    if (threadIdx.x < KG) {
        const int k = threadIdx.x;
        const float* p = params + (size_t)a * PROW;
        const float mux = p[k];
        const float muy = p[KG + k];
        // raw_sigma[a,k] = p[3K + 4k .. +3] as [[s00,s01],[s10,s11]]; L = tril
        // sigma = L L^T = [[s00^2, s00*s10],[s10*s00, s10^2+s11^2]]
        const float s00 = p[3 * KG + 4 * k + 0];
        const float s10 = p[3 * KG + 4 * k + 2];
        const float s11 = p[3 * KG + 4 * k + 3];
        const float srow0 = s00 * s00 + s00 * s10;
        const float srow1 = s10 * s00 + s10 * s10 + s11 * s11;
        // softmax over the K logits (each of the 16 threads scans all 16; trivial)
        float m = -INFINITY;
        #pragma unroll
        for (int j = 0; j < KG; ++j) m = fmaxf(m, p[2 * KG + j]);
        float denom = 0.0f;
        #pragma unroll
        for (int j = 0; j < KG; ++j) denom += __expf(p[2 * KG + j] - m);
        const float wk = __expf(p[2 * KG + k] - m) / denom;

        smux[k] = mux;
        smuy[k] = muy;
        ss0[k] = srow0;
        ss1[k] = srow1;
        swt[k] = wk;
    }
    __syncthreads();

    if (n >= N) return;

    // grid[n] = (xx[n // H], yy[n % H]); xx = linspace(0,1,W), yy = linspace(0,1,H)
    const int i = n / H;
    const int j = n - i * H;
    const float gx = (float)i / (float)(W - 1);
    const float gy = (float)j / (float)(H - 1);

    float esum = 0.0f, wsum = 0.0f;
    #pragma unroll
    for (int k = 0; k < KG; ++k) {
        const float dx = gx - smux[k];
        const float dy = gy - smuy[k];
        const float t1 = dx * ss0[k] + dy * ss1[k];
        const float t2 = dx + dy;
        const float e = __expf(-0.5f * t1 * t2);
        esum += e;
        wsum += swt[k] * e;
    }
    const float g = fmaxf(esum, 1e-8f);
    float y = wsum / g;
    y = fminf(fmaxf(y, 0.0f), 1.0f);
    out[(size_t)a * (size_t)N + n] = y;
}

extern "C" void kernel_launch(void* const* d_in, const int* in_sizes, int n_in,
                              void* d_out, int out_size, void* d_ws, size_t ws_size,
                              hipStream_t stream) {
    const float* params = (const float*)d_in[0];
    const int* hptr = (const int*)d_in[1];
    const int* wptr = (const int*)d_in[2];
    float* out = (float*)d_out;

    const int A = in_sizes[0] / PROW;       // B*CH = 24
    const int N = out_size / A;             // H*W = 65536
    dim3 block(256);
    dim3 grid((N + 255) / 256, A);
    moe_render_kernel<<<grid, block, 0, stream>>>(params, hptr, wptr, out, N);
}